// Round 6
// baseline (227.639 us; speedup 1.0000x reference)
//
#include <hip/hip_runtime.h>
#include <math.h>

// Problem constants
#define T_LEN 2048
#define BB    8
#define RS    256
#define DIN   1024
#define NE    768                 // 256 (W_proj) + 512 (W_res)
#define M_TOT (BB * T_LEN)        // 16384
#define LCH   32                  // scan chunk length
#define NCH   (T_LEN / LCH)       // 64 chunks
#define OUT_MAIN (M_TOT * 512)    // 8388608 floats, then final_r (2048), final_i (2048)

typedef unsigned short ushort;
typedef unsigned int   uint;
typedef short  short8  __attribute__((ext_vector_type(8)));
typedef float  f32x4   __attribute__((ext_vector_type(4)));
typedef ushort ushort8 __attribute__((ext_vector_type(8)));

// round-to-nearest-even fp32 -> bf16 bits
__device__ __forceinline__ ushort f2bf_rn(float x) {
    uint u = __float_as_uint(x);
    return (ushort)((u + 0x7FFFu + ((u >> 16) & 1u)) >> 16);
}
__device__ __forceinline__ float bf2f(ushort b) {
    return __uint_as_float(((uint)b) << 16);
}

// async global->LDS, 16 bytes per lane (lane-linear LDS dest required)
__device__ __forceinline__ void gload16(const ushort* g, ushort* l) {
    __builtin_amdgcn_global_load_lds(
        (const __attribute__((address_space(1))) uint*)g,
        (__attribute__((address_space(3))) uint*)l, 16, 0, 0);
}

// ---------------------------------------------------------------------------
// K0: fused split fp32 -> bf16 hi/lo for U, W_proj, W_res in one launch.
// ---------------------------------------------------------------------------
#define N8U  (M_TOT * DIN / 8)        // 2097152
#define N8WP (RS * DIN / 8)           // 32768
#define N8WR (2 * RS * DIN / 8)       // 65536
#define N8TOT (N8U + N8WP + N8WR)     // 2195456 = 8576 * 256

__global__ __launch_bounds__(256) void split_kernel(
    const float* __restrict__ u, const float* __restrict__ wp,
    const float* __restrict__ wr, ushort* __restrict__ Uhi,
    ushort* __restrict__ Ulo, ushort* __restrict__ Whi, ushort* __restrict__ Wlo)
{
    const int i = blockIdx.x * 256 + threadIdx.x;
    if (i >= N8TOT) return;
    const float* src; ushort* hi; ushort* lo; int j;
    if (i < N8U)              { src = u;  hi = Uhi; lo = Ulo; j = i; }
    else if (i < N8U + N8WP)  { src = wp; hi = Whi; lo = Wlo; j = i - N8U; }
    else                      { src = wr; hi = Whi + (size_t)RS * DIN;
                                lo = Wlo + (size_t)RS * DIN; j = i - N8U - N8WP; }
    const float4 x0 = ((const float4*)src)[(size_t)j * 2 + 0];
    const float4 x1 = ((const float4*)src)[(size_t)j * 2 + 1];
    const float xs[8] = {x0.x, x0.y, x0.z, x0.w, x1.x, x1.y, x1.z, x1.w};
    ushort8 hv, lv;
#pragma unroll
    for (int k = 0; k < 8; ++k) {
        const ushort hb = f2bf_rn(xs[k]);
        hv[k] = hb;
        lv[k] = f2bf_rn(xs[k] - bf2f(hb));
    }
    ((ushort8*)hi)[j] = hv;
    ((ushort8*)lo)[j] = lv;
}

// ---------------------------------------------------------------------------
// K1: bf16 3-term split MFMA GEMM — R5 version (80 us, MfmaUtil 42-44%,
//     FETCH 47 MB). m97 structure + bijective XCD swizzle. UNCHANGED.
// ---------------------------------------------------------------------------
#define Bb 128
#define BK 32

__global__ __launch_bounds__(256) void gemm_mfma(
    const ushort* __restrict__ Uh, const ushort* __restrict__ Ul,
    const ushort* __restrict__ Wh, const ushort* __restrict__ Wl,
    float* __restrict__ C)
{
    __shared__ ushort Ah[Bb * BK], Al[Bb * BK], Bh[Bb * BK], Bl[Bb * BK];
    const int tid  = threadIdx.x;
    const int id   = blockIdx.x;
    const int sid  = (id & 7) * 96 + (id >> 3);   // XCD-contiguous, bijective
    const int bn   = sid % 6;
    const int bm   = sid / 6;
    const int wid  = tid >> 6;
    const int lane = tid & 63;
    const int wr   = wid >> 1, wc = wid & 1;
    const int fr   = lane & 15;           // row/col within fragment
    const int fq   = lane >> 4;           // k-chunk 0..3

    const int srow = tid >> 2;            // 0..63
    const int skk  = (tid & 3) * 8;
    const ushort* gAh = Uh + (size_t)(bm * 128 + srow) * DIN + skk;
    const ushort* gAl = Ul + (size_t)(bm * 128 + srow) * DIN + skk;
    const ushort* gBh = Wh + (size_t)(bn * 128 + srow) * DIN + skk;
    const ushort* gBl = Wl + (size_t)(bn * 128 + srow) * DIN + skk;
    ushort* lAh0 = Ah + tid * 8; ushort* lAh1 = Ah + 64 * BK + tid * 8;
    ushort* lAl0 = Al + tid * 8; ushort* lAl1 = Al + 64 * BK + tid * 8;
    ushort* lBh0 = Bh + tid * 8; ushort* lBh1 = Bh + 64 * BK + tid * 8;
    ushort* lBl0 = Bl + tid * 8; ushort* lBl1 = Bl + 64 * BK + tid * 8;
    const size_t rstep = (size_t)64 * DIN;

    f32x4 acc[4][4];
#pragma unroll
    for (int m = 0; m < 4; ++m)
#pragma unroll
        for (int n = 0; n < 4; ++n) acc[m][n] = (f32x4){0.f, 0.f, 0.f, 0.f};

    for (int kk = 0; kk < DIN; kk += BK) {
        gload16(gAh + kk, lAh0); gload16(gAh + kk + rstep, lAh1);
        gload16(gAl + kk, lAl0); gload16(gAl + kk + rstep, lAl1);
        gload16(gBh + kk, lBh0); gload16(gBh + kk + rstep, lBh1);
        gload16(gBl + kk, lBl0); gload16(gBl + kk + rstep, lBl1);
        __syncthreads();   // drains vmcnt (compiler-emitted) — tiles ready

        short8 ah[4], al[4], bh[4], bl[4];
#pragma unroll
        for (int m = 0; m < 4; ++m) {
            const int row = wr * 64 + m * 16 + fr;
            ah[m] = *(const short8*)&Ah[row * BK + fq * 8];
            al[m] = *(const short8*)&Al[row * BK + fq * 8];
        }
#pragma unroll
        for (int n = 0; n < 4; ++n) {
            const int col = wc * 64 + n * 16 + fr;
            bh[n] = *(const short8*)&Bh[col * BK + fq * 8];
            bl[n] = *(const short8*)&Bl[col * BK + fq * 8];
        }
#pragma unroll
        for (int m = 0; m < 4; ++m)
#pragma unroll
            for (int n = 0; n < 4; ++n) {
                acc[m][n] = __builtin_amdgcn_mfma_f32_16x16x32_bf16(ah[m], bh[n], acc[m][n], 0, 0, 0);
                acc[m][n] = __builtin_amdgcn_mfma_f32_16x16x32_bf16(ah[m], bl[n], acc[m][n], 0, 0, 0);
                acc[m][n] = __builtin_amdgcn_mfma_f32_16x16x32_bf16(al[m], bh[n], acc[m][n], 0, 0, 0);
            }
        __syncthreads();   // readers done before next overwrite
    }

    // epilogue: C/D layout col=lane&15, row=(lane>>4)*4+reg  [m89/m91]
    const int crow0 = bm * 128 + wr * 64;
    const int ccol0 = bn * 128 + wc * 64;
#pragma unroll
    for (int m = 0; m < 4; ++m) {
        const int row = crow0 + m * 16 + fq * 4;
#pragma unroll
        for (int n = 0; n < 4; ++n) {
            const int col = ccol0 + n * 16 + fr;
#pragma unroll
            for (int j = 0; j < 4; ++j)
                C[(size_t)(row + j) * NE + col] = acc[m][n][j];
        }
    }
}

// ---------------------------------------------------------------------------
// complex pole per state r:  z = exp(lam) * (cos w, sin w),  lam = -5*sigmoid(lraw)
// ---------------------------------------------------------------------------
__device__ inline void pole(const float* __restrict__ lraw, const float* __restrict__ om,
                            int r, float& zr, float& zi, float& lam, float& o)
{
    const float x   = lraw[r];
    const float sig = 1.f / (1.f + expf(-x));
    lam = -5.f * sig;
    o   = om[r];
    const float er = expf(lam);
    zr = er * cosf(o);
    zi = er * sinf(o);
}

// ---------------------------------------------------------------------------
// K2: per-chunk carries — direct coalesced strided reads, unroll-8. UNCHANGED.
// ---------------------------------------------------------------------------
__global__ __launch_bounds__(256) void carry_kernel(
    const float* __restrict__ C, const float* __restrict__ lraw,
    const float* __restrict__ om, float2* __restrict__ carry)
{
    const int c = blockIdx.x, b = blockIdx.y, r = threadIdx.x;
    const int m0 = b * T_LEN + c * LCH;
    float zr, zi, lam, o;
    pole(lraw, om, r, zr, zi, lam, o);
    const float* p = C + (size_t)m0 * NE + r;
    float hr = 0.f, hi = 0.f;
#pragma unroll 8
    for (int s = 0; s < LCH; ++s) {
        const float u  = p[(size_t)s * NE];
        const float nr = zr * hr - zi * hi + u;
        const float ni = zr * hi + zi * hr;
        hr = nr; hi = ni;
    }
    carry[(size_t)(b * NCH + c) * RS + r] = make_float2(hr, hi);
}

// ---------------------------------------------------------------------------
// K3 v4: fused prefix + re-scan + residual + LayerNorm, 512 threads.
//   Waves 0-3 (scan): hold all 32 u values in regs (32 independent coalesced
//     loads issued up front), compute entry state via PIPELINED weighted sum
//     S(c) = sum_j zL^(c-1-j)*carry_j + h0*zL^c (loads batched 8-deep; only
//     the weight chain is serial), then run the recurrence (pure VALU).
//   Waves 4-7 (loaders): stream residual channels (C cols 256..767) into LDS,
//     prefetching batch k+1 into regs during batch k's LN (T14).
//   LN: 8 waves x 1 row per batch, shfl-tree reduce, float4 stores.
//   Block c=63 writes final_r/final_i.
// ---------------------------------------------------------------------------
__global__ __launch_bounds__(512) void scan_ln_kernel(
    const float* __restrict__ C, const float2* __restrict__ carry,
    const float* __restrict__ h0r, const float* __restrict__ h0i,
    const float* __restrict__ lraw, const float* __restrict__ om,
    const float* __restrict__ gamma, const float* __restrict__ beta,
    float* __restrict__ out)
{
    const int c = blockIdx.x, b = blockIdx.y, tid = threadIdx.x;
    __shared__ float xt[8][512];   // h values: [row][hr(256) | hi(256)]
    __shared__ float rt[8][512];   // residual channels
    const int m0   = b * T_LEN + c * LCH;
    const int wid  = tid >> 6, lane = tid & 63;
    const bool isScan = (tid < 256);
    const int r    = tid & 255;

    // LN params (all threads): channels lane*8 .. lane*8+7
    const float4 g0  = *(const float4*)&gamma[lane * 8];
    const float4 g1  = *(const float4*)&gamma[lane * 8 + 4];
    const float4 be0 = *(const float4*)&beta[lane * 8];
    const float4 be1 = *(const float4*)&beta[lane * 8 + 4];

    float   uu[32];
    float2  st = make_float2(0.f, 0.f);
    float   zr = 0.f, zi = 0.f;
    float2  resreg[8];

    if (isScan) {
        // issue all 32 u loads (independent, coalesced, fill the vmem queue)
        const float* up = C + (size_t)m0 * NE + r;
#pragma unroll
        for (int s = 0; s < 32; ++s) uu[s] = up[(size_t)s * NE];

        float lam, o;
        pole(lraw, om, r, zr, zi, lam, o);
        const float eL  = expf(lam * (float)LCH);
        const float zLr = eL * cosf(o * (float)LCH);
        const float zLi = eL * sinf(o * (float)LCH);

        // phase A: weighted sum over carries, loads pipelined 8-deep
        float ar = 0.f, ai = 0.f;
        float wr_ = 1.f, wi_ = 0.f;          // running zL^k
        const float2* cp = carry + (size_t)b * NCH * RS + r;
        int j = c - 1;
        for (; j >= 7; j -= 8) {
            float2 k[8];
#pragma unroll
            for (int t = 0; t < 8; ++t) k[t] = cp[(size_t)(j - t) * RS];
#pragma unroll
            for (int t = 0; t < 8; ++t) {
                ar += wr_ * k[t].x - wi_ * k[t].y;
                ai += wr_ * k[t].y + wi_ * k[t].x;
                const float nwr = wr_ * zLr - wi_ * zLi;
                const float nwi = wr_ * zLi + wi_ * zLr;
                wr_ = nwr; wi_ = nwi;
            }
        }
        for (; j >= 0; --j) {
            const float2 k = cp[(size_t)j * RS];
            ar += wr_ * k.x - wi_ * k.y;
            ai += wr_ * k.y + wi_ * k.x;
            const float nwr = wr_ * zLr - wi_ * zLi;
            const float nwi = wr_ * zLi + wi_ * zLr;
            wr_ = nwr; wi_ = nwi;
        }
        // after the loop w = zL^c : add h0 ZIR term
        const float h0R = h0r[b * RS + r];
        const float h0I = h0i[b * RS + r];
        st.x = ar + h0R * wr_ - h0I * wi_;
        st.y = ai + h0R * wi_ + h0I * wr_;
    } else {
        // loaders: preload batch 0 residuals (8 rows x float2 per thread)
        const float* rp = C + (size_t)m0 * NE + 256 + 2 * r;
#pragma unroll
        for (int s = 0; s < 8; ++s)
            resreg[s] = *(const float2*)(rp + (size_t)s * NE);
    }

#pragma unroll
    for (int batch = 0; batch < 4; ++batch) {
        if (isScan) {
            // scan 8 steps (pure VALU, u in regs), write h into xt
#pragma unroll
            for (int s = 0; s < 8; ++s) {
                const float u  = uu[batch * 8 + s];
                const float hr = zr * st.x - zi * st.y + u;
                const float hi = zr * st.y + zi * st.x;
                st.x = hr; st.y = hi;
                xt[s][r]       = hr;
                xt[s][256 + r] = hi;
            }
        } else {
            // write this batch's residuals from regs into LDS
#pragma unroll
            for (int s = 0; s < 8; ++s)
                *(float2*)&rt[s][2 * r] = resreg[s];
        }
        __syncthreads();   // xt, rt ready

        // loaders: issue next batch's loads now (hidden under LN)
        if (!isScan && batch < 3) {
            const float* rp = C + (size_t)(m0 + (batch + 1) * 8) * NE + 256 + 2 * r;
#pragma unroll
            for (int s = 0; s < 8; ++s)
                resreg[s] = *(const float2*)(rp + (size_t)s * NE);
        }

        // LN: wave wid owns row wid of this batch
        {
            const int s = wid;
            const int m = m0 + batch * 8 + s;
            const float4 ha = *(const float4*)&xt[s][lane * 8];
            const float4 hb = *(const float4*)&xt[s][lane * 8 + 4];
            const float4 ra = *(const float4*)&rt[s][lane * 8];
            const float4 rb = *(const float4*)&rt[s][lane * 8 + 4];
            float4 x0, x1;
            x0.x = ha.x + ra.x; x0.y = ha.y + ra.y; x0.z = ha.z + ra.z; x0.w = ha.w + ra.w;
            x1.x = hb.x + rb.x; x1.y = hb.y + rb.y; x1.z = hb.z + rb.z; x1.w = hb.w + rb.w;
            float s1 = (x0.x + x0.y) + (x0.z + x0.w) + (x1.x + x1.y) + (x1.z + x1.w);
            float s2 = (x0.x * x0.x + x0.y * x0.y) + (x0.z * x0.z + x0.w * x0.w)
                     + (x1.x * x1.x + x1.y * x1.y) + (x1.z * x1.z + x1.w * x1.w);
#pragma unroll
            for (int off = 1; off < 64; off <<= 1) {
                s1 += __shfl_xor(s1, off);
                s2 += __shfl_xor(s2, off);
            }
            const float mu   = s1 * (1.f / 512.f);
            const float var  = s2 * (1.f / 512.f) - mu * mu;
            const float rstd = rsqrtf(var + 1e-5f);
            float4 o0, o1;
            o0.x = (x0.x - mu) * rstd * g0.x + be0.x;
            o0.y = (x0.y - mu) * rstd * g0.y + be0.y;
            o0.z = (x0.z - mu) * rstd * g0.z + be0.z;
            o0.w = (x0.w - mu) * rstd * g0.w + be0.w;
            o1.x = (x1.x - mu) * rstd * g1.x + be1.x;
            o1.y = (x1.y - mu) * rstd * g1.y + be1.y;
            o1.z = (x1.z - mu) * rstd * g1.z + be1.z;
            o1.w = (x1.w - mu) * rstd * g1.w + be1.w;
            *(float4*)&out[(size_t)m * 512 + lane * 8]     = o0;
            *(float4*)&out[(size_t)m * 512 + lane * 8 + 4] = o1;
        }
        __syncthreads();   // xt/rt reuse next batch
    }

    if (c == NCH - 1 && isScan) {   // st = h[T-1]
        out[OUT_MAIN + b * RS + r]           = st.x;   // final_r
        out[OUT_MAIN + BB * RS + b * RS + r] = st.y;   // final_i
    }
}

// ---------------------------------------------------------------------------
extern "C" void kernel_launch(void* const* d_in, const int* in_sizes, int n_in,
                              void* d_out, int out_size, void* d_ws, size_t ws_size,
                              hipStream_t stream)
{
    const float* u    = (const float*)d_in[0];
    const float* h0r  = (const float*)d_in[1];
    const float* h0i  = (const float*)d_in[2];
    const float* lraw = (const float*)d_in[3];
    const float* omg  = (const float*)d_in[4];
    const float* Wp   = (const float*)d_in[5];
    const float* Wr   = (const float*)d_in[6];
    const float* gam  = (const float*)d_in[7];
    const float* bet  = (const float*)d_in[8];
    float* out = (float*)d_out;

    // workspace layout (~122 MB):
    float*  C     = (float*)d_ws;                       // 16384*768 f32 (50.3 MB)
    float2* carry = (float2*)(C + (size_t)M_TOT * NE);  // 1 MB
    ushort* Uhi   = (ushort*)(carry + (size_t)BB * NCH * RS);
    ushort* Ulo   = Uhi + (size_t)M_TOT * DIN;          // 33.5 MB each
    ushort* Whi   = Ulo + (size_t)M_TOT * DIN;          // 1.57 MB
    ushort* Wlo   = Whi + (size_t)NE * DIN;             // 1.57 MB

    split_kernel<<<N8TOT / 256, 256, 0, stream>>>(u, Wp, Wr, Uhi, Ulo, Whi, Wlo);
    gemm_mfma<<<768, 256, 0, stream>>>(Uhi, Ulo, Whi, Wlo, C);
    carry_kernel<<<dim3(NCH, BB), 256, 0, stream>>>(C, lraw, omg, carry);
    scan_ln_kernel<<<dim3(NCH, BB), 512, 0, stream>>>(C, (const float2*)carry,
                                                      h0r, h0i, lraw, omg, gam, bet, out);
}